// Round 2
// baseline (834.399 us; speedup 1.0000x reference)
//
#include <hip/hip_runtime.h>
#include <math.h>

// Problem shape: N=524288 nodes, D=256, H=128, B=2048. Batch is sorted.
#define DD 256
#define HH 128
#define NT 8           // 8 n-tiles of 16 cols = 128 hidden dims

typedef short bf16x8 __attribute__((ext_vector_type(8)));   // 8 bf16 (4 VGPRs)
typedef float f32x4  __attribute__((ext_vector_type(4)));   // MFMA accum

// ---- bf16 split helpers (RNE) --------------------------------------------
__device__ __forceinline__ unsigned short f32_to_bf16_rne(float f) {
    unsigned u = __float_as_uint(f);
    unsigned r = u + 0x7FFFu + ((u >> 16) & 1u);
    return (unsigned short)(r >> 16);
}
__device__ __forceinline__ void split_bf16(float f, unsigned short& hi,
                                           unsigned short& lo) {
    unsigned u = __float_as_uint(f);
    unsigned r = u + 0x7FFFu + ((u >> 16) & 1u);
    hi = (unsigned short)(r >> 16);
    float hf = __uint_as_float(r & 0xFFFF0000u);
    lo = f32_to_bf16_rne(f - hf);
}
__device__ __forceinline__ float tanh_fast(float a) {
    float e = __expf(2.0f * a);
    return 1.0f - __fdividef(2.0f, e + 1.0f);
}

// ---------------------------------------------------------------------------
// Kernel 0: pack W1 (fp32 [256][128]) into MFMA-B-fragment-ready bf16 hi/lo.
// Layout: Wpk[s][t][nt][lane][i]  (s=split 0:hi 1:lo, t=kstep 0..7, nt=0..7)
//   value = split_s( W1[k][j] ), k = t*32 + (lane>>4)*8 + i, j = nt*16 + (lane&15)
// Flat shorts: s*32768 + t*4096 + nt*512 + lane*8 + i
// ---------------------------------------------------------------------------
__global__ __launch_bounds__(256) void pack_w1_kernel(
    const float* __restrict__ W1, unsigned short* __restrict__ Wpk)
{
    int tid = blockIdx.x * 256 + threadIdx.x;      // 0..32767
    int i  = tid & 7;
    int l  = (tid >> 3) & 63;
    int nt = (tid >> 9) & 7;
    int t  = tid >> 12;
    int k = t * 32 + ((l >> 4) << 3) + i;
    int j = nt * 16 + (l & 15);
    unsigned short hb, lb;
    split_bf16(W1[k * HH + j], hb, lb);
    Wpk[tid]         = hb;     // s=0
    Wpk[32768 + tid] = lb;     // s=1
}

// ---------------------------------------------------------------------------
// Kernel 1: scores[n] = tanh(x[n,:] @ W1 + b1) @ W2 + b2  via split-bf16 MFMA.
// Block = 256 threads = 4 waves; wave handles 32 rows (2 m-tiles of 16).
// K-loop: 8 steps of K=32; W-slice (16 KB: hi+lo) double-buffered in LDS.
// Epilogue fused: tanh + dot(W2) + 16-lane shfl reduce.
// ---------------------------------------------------------------------------
__global__ __launch_bounds__(256) void scores_mfma_kernel(
    const float* __restrict__ x, const unsigned short* __restrict__ Wpk,
    const float* __restrict__ b1, const float* __restrict__ W2,
    const float* __restrict__ b2, float* __restrict__ scores, int n)
{
    __shared__ unsigned short lds[2][8192];        // 2 bufs x 16 KB

    const int w   = threadIdx.x >> 6;              // wave 0..3
    const int l   = threadIdx.x & 63;
    const int lhi = l >> 4;                        // 0..3
    const int llo = l & 15;
    const int rowbase = blockIdx.x * 128 + w * 32;

    // ---- stage W-slice for kstep t into buffer b (reg staging, 4 waves split 16 chunks)
    auto stage = [&](int t, int b) {
#pragma unroll
        for (int q = 0; q < 4; ++q) {
            int idx = w * 4 + q;                   // 0..15
            int s = idx >> 3, c = idx & 7;
            const bf16x8* g = (const bf16x8*)(Wpk + (size_t)s * 32768 +
                                              t * 4096 + c * 512 + l * 8);
            *(bf16x8*)&lds[b][s * 4096 + c * 512 + l * 8] = *g;
        }
    };

    // ---- A (x) prefetch registers: 2 m-tiles x 8 floats/lane
    float4 xa[2], xb[2];
    auto load_x = [&](int t) {
#pragma unroll
        for (int mt = 0; mt < 2; ++mt) {
            int row = rowbase + mt * 16 + llo;
            if (row > n - 1) row = n - 1;
            const float* xp = x + (size_t)row * DD + t * 32 + lhi * 8;
            xa[mt] = *(const float4*)xp;
            xb[mt] = *(const float4*)(xp + 4);
        }
    };

    f32x4 acc[2][NT];
#pragma unroll
    for (int mt = 0; mt < 2; ++mt)
#pragma unroll
        for (int nt = 0; nt < NT; ++nt) acc[mt][nt] = (f32x4){0.f, 0.f, 0.f, 0.f};

    load_x(0);
    stage(0, 0);

    for (int t = 0; t < 8; ++t) {
        __syncthreads();
        if (t < 7) stage(t + 1, (t + 1) & 1);

        // convert current x regs -> bf16 hi/lo A fragments
        bf16x8 ah[2], al[2];
#pragma unroll
        for (int mt = 0; mt < 2; ++mt) {
            float xv[8] = {xa[mt].x, xa[mt].y, xa[mt].z, xa[mt].w,
                           xb[mt].x, xb[mt].y, xb[mt].z, xb[mt].w};
#pragma unroll
            for (int i = 0; i < 8; ++i) {
                unsigned short hb, lb;
                split_bf16(xv[i], hb, lb);
                ah[mt][i] = (short)hb;
                al[mt][i] = (short)lb;
            }
        }
        if (t < 7) load_x(t + 1);                  // issue next global loads early

        const int b = t & 1;
#pragma unroll
        for (int nt = 0; nt < NT; ++nt) {
            bf16x8 bh = *(const bf16x8*)&lds[b][0 * 4096 + nt * 512 + l * 8];
            bf16x8 bl = *(const bf16x8*)&lds[b][1 * 4096 + nt * 512 + l * 8];
#pragma unroll
            for (int mt = 0; mt < 2; ++mt) {
                acc[mt][nt] = __builtin_amdgcn_mfma_f32_16x16x32_bf16(ah[mt], bh, acc[mt][nt], 0, 0, 0);
                acc[mt][nt] = __builtin_amdgcn_mfma_f32_16x16x32_bf16(ah[mt], bl, acc[mt][nt], 0, 0, 0);
                acc[mt][nt] = __builtin_amdgcn_mfma_f32_16x16x32_bf16(al[mt], bh, acc[mt][nt], 0, 0, 0);
            }
        }
    }

    // ---- fused epilogue: s = b2 + sum_j tanh(h_j + b1_j) * W2_j
    // D layout: col j = nt*16 + llo ; row (node) = mt*16 + lhi*4 + r
    const float b2v = b2[0];
    float b1v[NT], w2v[NT];
#pragma unroll
    for (int nt = 0; nt < NT; ++nt) {
        b1v[nt] = b1[nt * 16 + llo];
        w2v[nt] = W2[nt * 16 + llo];
    }
#pragma unroll
    for (int mt = 0; mt < 2; ++mt) {
#pragma unroll
        for (int r = 0; r < 4; ++r) {
            float v = 0.f;
#pragma unroll
            for (int nt = 0; nt < NT; ++nt)
                v = fmaf(tanh_fast(acc[mt][nt][r] + b1v[nt]), w2v[nt], v);
            v += __shfl_xor(v, 1);
            v += __shfl_xor(v, 2);
            v += __shfl_xor(v, 4);
            v += __shfl_xor(v, 8);
            int node = rowbase + mt * 16 + lhi * 4 + r;
            if (llo == 0 && node < n) scores[node] = v + b2v;
        }
    }
}

// ---------------------------------------------------------------------------
// Kernel 2: per-segment softmax over scores (batch sorted). Block per segment.
// ---------------------------------------------------------------------------
__device__ __forceinline__ int lower_bound_i32(const int* __restrict__ arr,
                                               int n, int val)
{
    int lo = 0, hi = n;
    while (lo < hi) {
        int mid = (lo + hi) >> 1;
        if (arr[mid] < val) lo = mid + 1; else hi = mid;
    }
    return lo;
}

__global__ __launch_bounds__(256) void seg_softmax_kernel(
    float* __restrict__ scores, const int* __restrict__ batch,
    int* __restrict__ seg_start, int* __restrict__ seg_end, int n)
{
    int b = blockIdx.x;
    int start = lower_bound_i32(batch, n, b);
    int end   = lower_bound_i32(batch, n, b + 1);
    int tid = threadIdx.x;
    int wid = tid >> 6;

    __shared__ float redmax[4];
    __shared__ float redsum[4];

    float m = -INFINITY;
    for (int i = start + tid; i < end; i += 256) m = fmaxf(m, scores[i]);
#pragma unroll
    for (int o = 32; o > 0; o >>= 1) m = fmaxf(m, __shfl_xor(m, o));
    if ((tid & 63) == 0) redmax[wid] = m;
    __syncthreads();
    m = fmaxf(fmaxf(redmax[0], redmax[1]), fmaxf(redmax[2], redmax[3]));

    float sum = 0.f;
    for (int i = start + tid; i < end; i += 256) sum += expf(scores[i] - m);
#pragma unroll
    for (int o = 32; o > 0; o >>= 1) sum += __shfl_xor(sum, o);
    if ((tid & 63) == 0) redsum[wid] = sum;
    __syncthreads();
    sum = redsum[0] + redsum[1] + redsum[2] + redsum[3];

    float inv = (end > start) ? 1.0f / sum : 0.f;
    for (int i = start + tid; i < end; i += 256)
        scores[i] = expf(scores[i] - m) * inv;

    if (tid == 0) { seg_start[b] = start; seg_end[b] = end; }
}

// ---------------------------------------------------------------------------
// Kernel 3: pooled[b,d] = sum_{i in seg b} x[i,d] * w[i]. Block/segment,
// thread = dim; coalesced 1 KB/node; w[i] wave-uniform (scalar broadcast).
// ---------------------------------------------------------------------------
__global__ __launch_bounds__(256) void pool_kernel(
    const float* __restrict__ x, const float* __restrict__ w,
    const int* __restrict__ seg_start, const int* __restrict__ seg_end,
    float* __restrict__ out)
{
    int b = blockIdx.x;
    int d = threadIdx.x;
    int start = seg_start[b];
    int end   = seg_end[b];

    float acc = 0.f;
    int i = start;
    for (; i + 4 <= end; i += 4) {
        float w0 = w[i], w1 = w[i + 1], w2 = w[i + 2], w3 = w[i + 3];
        acc = fmaf(x[(size_t)(i + 0) * DD + d], w0, acc);
        acc = fmaf(x[(size_t)(i + 1) * DD + d], w1, acc);
        acc = fmaf(x[(size_t)(i + 2) * DD + d], w2, acc);
        acc = fmaf(x[(size_t)(i + 3) * DD + d], w3, acc);
    }
    for (; i < end; ++i)
        acc = fmaf(x[(size_t)i * DD + d], w[i], acc);

    out[(size_t)b * DD + d] = acc;
}

// ---------------------------------------------------------------------------
extern "C" void kernel_launch(void* const* d_in, const int* in_sizes, int n_in,
                              void* d_out, int out_size, void* d_ws, size_t ws_size,
                              hipStream_t stream)
{
    const float* x     = (const float*)d_in[0];
    const int*   batch = (const int*)  d_in[1];
    const float* W1    = (const float*)d_in[2];
    const float* b1    = (const float*)d_in[3];
    const float* W2    = (const float*)d_in[4];
    const float* b2    = (const float*)d_in[5];
    float* out = (float*)d_out;

    int n    = in_sizes[1];
    int Bseg = out_size / DD;

    // ws layout: scores [n] f32 | seg_start/end [Bseg] i32 | Wpk 65536 bf16
    float* scores    = (float*)d_ws;
    int*   seg_start = (int*)((char*)d_ws + (size_t)n * 4);
    int*   seg_end   = seg_start + Bseg;
    unsigned short* Wpk = (unsigned short*)((char*)d_ws + (size_t)n * 4 + (size_t)Bseg * 8);

    pack_w1_kernel<<<128, 256, 0, stream>>>(W1, Wpk);
    scores_mfma_kernel<<<(n + 127) / 128, 256, 0, stream>>>(x, Wpk, b1, W2, b2,
                                                            scores, n);
    seg_softmax_kernel<<<Bseg, 256, 0, stream>>>(scores, batch,
                                                 seg_start, seg_end, n);
    pool_kernel<<<Bseg, 256, 0, stream>>>(x, scores, seg_start, seg_end, out);
}